// Round 8
// baseline (289.813 us; speedup 1.0000x reference)
//
#include <hip/hip_runtime.h>

#define N_NODES_C 50000
#define N_EDGES_C 800000
#define N_EDGES2_C (2 * N_EDGES_C)
#define D 128
#define NSHARD 8
#define OFCAP 4096 // overflow list capacity (expected use ~3 edges)

// Bucketed append: BROWS rows per bucket, per-XCD sub-buckets.
#define BROWS 4
#define NBKT (N_NODES_C / BROWS)   // 12500 (exact)
#define NSB (NSHARD * NBKT)        // 100000 sub-buckets
#define BCAP 32                    // entries per sub-bucket (mean 16, +4 sigma)

#define GNODES 64
#define LDP 132                                            // pad: multiple of 4 floats
#define GGRID ((N_NODES_C + GNODES - 1) / GNODES)          // 782 gemm blocks
#define FGRID 2048                                         // fill blocks
#define FEPB ((N_EDGES2_C + FGRID - 1) / FGRID)            // 782 edges/block
#define TOTG (GGRID + FGRID)                               // 2830

static __device__ __forceinline__ unsigned short f2bf(float f) {
  unsigned u = __float_as_uint(f);
  u += 0x7fff + ((u >> 16) & 1);  // round-to-nearest-even
  return (unsigned short)(u >> 16);
}
static __device__ __forceinline__ float bf_lo(unsigned u) {
  return __uint_as_float(u << 16);
}
static __device__ __forceinline__ float bf_hi(unsigned u) {
  return __uint_as_float(u & 0xffff0000u);
}

// Physical XCD id (0..7), wave-uniform; steers L2 locality only.
static __device__ __forceinline__ int xcd_id() {
  int v;
  asm volatile("s_getreg_b32 %0, hwreg(HW_REG_XCC_ID, 0, 4)" : "=s"(v));
  return v & (NSHARD - 1);
}

// ---------------------------------------------------------------------------
// Kernel 1: alpha[i] = sigmoid(dot(x[i], alpha_w) + alpha_b), wave per node,
// PLUS zeroing of bcursor[NSB] and ofcnt (adjacent in ws). (Round-6 verified;
// round-7's alpha-in-gemm-block was 19 us SLOWER — serial wave-reduce chain
// on the gemm blocks' critical path.)
// ---------------------------------------------------------------------------
__global__ __launch_bounds__(256) void alpha_zero_kernel(
    const float* __restrict__ x,
    const float* __restrict__ aw,
    const float* __restrict__ ab,
    float* __restrict__ alpha_out,
    float* __restrict__ alpha_ws,
    int* __restrict__ bcursor,   // zeroes [0, NSB + 64) ints (incl ofcnt)
    int n) {
  int gtid = blockIdx.x * blockDim.x + threadIdx.x;
  if (gtid < NSB + 64) bcursor[gtid] = 0;

  int wave = gtid >> 6;
  int lane = threadIdx.x & 63;
  if (wave >= n) return;
  const float* xr = x + (size_t)wave * D;
  float s = xr[lane] * aw[lane] + xr[lane + 64] * aw[lane + 64];
  #pragma unroll
  for (int off = 32; off > 0; off >>= 1)
    s += __shfl_down(s, off);
  if (lane == 0) {
    float a = 1.0f / (1.0f + __expf(-(s + ab[0])));
    alpha_out[wave] = a;
    alpha_ws[wave] = a;
  }
}

// ---------------------------------------------------------------------------
// Kernel 2 (FUSED, block-specialized): GGRID gemm blocks + FGRID fill blocks,
// Bresenham-interleaved. (Round-6 verified body, reverted from round 7.)
// ---------------------------------------------------------------------------
__global__ __launch_bounds__(256) void gemm_fill_kernel(
    const float* __restrict__ x,
    const float* __restrict__ W,
    unsigned* __restrict__ y,        // [N][64] packed words
    const int* __restrict__ lp_rows, const int* __restrict__ lp_cols,
    const float* __restrict__ lp_vals,
    const int* __restrict__ hp_rows, const int* __restrict__ hp_cols,
    const float* __restrict__ hp_vals,
    const float* __restrict__ alpha,
    int* __restrict__ bcursor,       // [NSB], zeroed
    uint2* __restrict__ bins,        // [NSB][BCAP]
    int* __restrict__ ofcnt,
    uint2* __restrict__ ofl,
    int n) {
  __shared__ float zs[GNODES][LDP];  // 33.8 KB
  __shared__ float wt[64][LDP];      // 33.8 KB (one j-half of W)

  int t = threadIdx.x;
  int bid = blockIdx.x;
  // Bresenham role split: exactly GGRID gemm blocks spread evenly.
  int g = (bid * GGRID) / TOTG;
  int gn = ((bid + 1) * GGRID) / TOTG;

  if (gn > g) {
    // ---------------- gemm block: nodes [g*64, g*64+64) ----------------
    int node0 = g * GNODES;
    int tn = t & 15;
    int tjg = t >> 4;   // 0..15
    int jb = tjg * 4;   // local j base within this half

    #pragma unroll
    for (int it = 0; it < 8; ++it) {
      int f = t + it * 256;
      int r = f >> 5;
      int c4 = f & 31;
      int node = node0 + r;
      float4 v = make_float4(0.f, 0.f, 0.f, 0.f);
      if (node < n) v = ((const float4*)(x + (size_t)node * D))[c4];
      *(float4*)&zs[r][c4 * 4] = v;
    }

    for (int jh = 0; jh < 2; ++jh) {
      if (jh) __syncthreads();  // half 0's wt readers done before overwrite
      #pragma unroll
      for (int it = 0; it < 8; ++it) {
        int f = t + it * 256;
        int j = f >> 5;
        int k4 = f & 31;
        *(float4*)&wt[j][k4 * 4] =
            ((const float4*)W)[(size_t)(jh * 64 + j) * 32 + k4];
      }
      __syncthreads();

      float acc[4][4] = {};
      #pragma unroll 2
      for (int k = 0; k < D; k += 4) {
        float4 w0 = *(const float4*)&wt[jb + 0][k];
        float4 w1 = *(const float4*)&wt[jb + 1][k];
        float4 w2 = *(const float4*)&wt[jb + 2][k];
        float4 w3 = *(const float4*)&wt[jb + 3][k];
        float4 z0 = *(const float4*)&zs[tn][k];
        float4 z1 = *(const float4*)&zs[tn + 16][k];
        float4 z2 = *(const float4*)&zs[tn + 32][k];
        float4 z3 = *(const float4*)&zs[tn + 48][k];
        acc[0][0] += z0.x*w0.x + z0.y*w0.y + z0.z*w0.z + z0.w*w0.w;
        acc[0][1] += z0.x*w1.x + z0.y*w1.y + z0.z*w1.z + z0.w*w1.w;
        acc[0][2] += z0.x*w2.x + z0.y*w2.y + z0.z*w2.z + z0.w*w2.w;
        acc[0][3] += z0.x*w3.x + z0.y*w3.y + z0.z*w3.z + z0.w*w3.w;
        acc[1][0] += z1.x*w0.x + z1.y*w0.y + z1.z*w0.z + z1.w*w0.w;
        acc[1][1] += z1.x*w1.x + z1.y*w1.y + z1.z*w1.z + z1.w*w1.w;
        acc[1][2] += z1.x*w2.x + z1.y*w2.y + z1.z*w2.z + z1.w*w2.w;
        acc[1][3] += z1.x*w3.x + z1.y*w3.y + z1.z*w3.z + z1.w*w3.w;
        acc[2][0] += z2.x*w0.x + z2.y*w0.y + z2.z*w0.z + z2.w*w0.w;
        acc[2][1] += z2.x*w1.x + z2.y*w1.y + z2.z*w1.z + z2.w*w1.w;
        acc[2][2] += z2.x*w2.x + z2.y*w2.y + z2.z*w2.z + z2.w*w2.w;
        acc[2][3] += z2.x*w3.x + z2.y*w3.y + z2.z*w3.z + z2.w*w3.w;
        acc[3][0] += z3.x*w0.x + z3.y*w0.y + z3.z*w0.z + z3.w*w0.w;
        acc[3][1] += z3.x*w1.x + z3.y*w1.y + z3.z*w1.z + z3.w*w1.w;
        acc[3][2] += z3.x*w2.x + z3.y*w2.y + z3.z*w2.z + z3.w*w2.w;
        acc[3][3] += z3.x*w3.x + z3.y*w3.y + z3.z*w3.z + z3.w*w3.w;
      }

      #pragma unroll
      for (int ii = 0; ii < 4; ++ii) {
        int node = node0 + ii * 16 + tn;
        if (node < n) {
          uint2 o;
          o.x = (unsigned)f2bf(acc[ii][0]) | ((unsigned)f2bf(acc[ii][1]) << 16);
          o.y = (unsigned)f2bf(acc[ii][2]) | ((unsigned)f2bf(acc[ii][3]) << 16);
          *(uint2*)&y[(size_t)node * 64 + jh * 32 + tjg * 2] = o;
        }
      }
    }
  } else {
    // ---------------- fill block: edges [fb*FEPB, fb*FEPB+FEPB) --------
    int fb = bid - g;
    int xcc = xcd_id();
    int e0 = fb * FEPB;
    int e1 = e0 + FEPB;
    if (e1 > N_EDGES2_C) e1 = N_EDGES2_C;
    for (int e = e0 + t; e < e1; e += 256) {
      int r, c;
      float v;
      if (e < N_EDGES_C) {
        r = __builtin_nontemporal_load(lp_rows + e);
        c = __builtin_nontemporal_load(lp_cols + e);
        v = __builtin_nontemporal_load(lp_vals + e) * alpha[r];
      } else {
        int i = e - N_EDGES_C;
        r = __builtin_nontemporal_load(hp_rows + i);
        c = __builtin_nontemporal_load(hp_cols + i);
        v = __builtin_nontemporal_load(hp_vals + i) * (1.0f - alpha[r]);
      }
      int sb = xcc * NBKT + (r >> 2);
      int p = atomicAdd(&bcursor[sb], 1);
      if (p < BCAP) {
        bins[(size_t)sb * BCAP + p] =
            make_uint2(((unsigned)r << 16) | (unsigned)c, __float_as_uint(v));
      } else {
        int q = atomicAdd(ofcnt, 1);
        if (q < OFCAP)
          ofl[q] = make_uint2(((unsigned)r << 16) | (unsigned)c,
                              (unsigned)__float_as_int(v));
      }
    }
  }
}

// ---------------------------------------------------------------------------
// Kernel 3: gather — ONE BLOCK (512 thr, 8 waves) PER BUCKET; wave w drains
// sub-bucket (shard w, bucket b): ~16 edges, 4 independent y-loads in flight
// -> ~4 dependent steps/wave and 100k productive waves (round-6's 12.5k
// waves x 128-edge chains was the latency-hiding collapse: gather ~95 us vs
// round-5's ~80 at identical traffic). Named per-row register accumulators
// (readfirstlane + scalar switch, no divergence); partials combined via
// 16 KB LDS tree with plain writes + syncthreads (NO FP atomics — round-4
// lesson). 512 thr + 16 KB -> 4 blocks/CU = full 32 waves/CU.
// ---------------------------------------------------------------------------
__global__ __launch_bounds__(512) void gather_kernel(
    const int* __restrict__ bcursor,     // [NSHARD][NBKT]
    const uint2* __restrict__ bins,      // [NSB][BCAP]
    const unsigned* __restrict__ y,      // [N][64], word q = dims (2q,2q+1)
    const float* __restrict__ bias,
    const int* __restrict__ ofcnt,
    const uint2* __restrict__ ofl,
    float* __restrict__ out) {
  __shared__ float2 part[8][4][64];  // 16 KB
  int t = threadIdx.x;
  int w = t >> 6;      // wave 0..7 = shard
  int lane = t & 63;
  int bkt = blockIdx.x;

  float a0L = 0.f, a0H = 0.f, a1L = 0.f, a1H = 0.f;
  float a2L = 0.f, a2H = 0.f, a3L = 0.f, a3H = 0.f;

  #define ACC(RR, VV, UU)                                        \
    do {                                                         \
      float uL_ = bf_lo(UU), uH_ = bf_hi(UU);                    \
      switch (RR) {                                              \
        case 0: a0L += (VV) * uL_; a0H += (VV) * uH_; break;     \
        case 1: a1L += (VV) * uL_; a1H += (VV) * uH_; break;     \
        case 2: a2L += (VV) * uL_; a2H += (VV) * uH_; break;     \
        default: a3L += (VV) * uL_; a3H += (VV) * uH_; break;    \
      }                                                          \
    } while (0)

  int sb = w * NBKT + bkt;
  int cnt = bcursor[sb];
  if (cnt > BCAP) cnt = BCAP;
  uint2 wv = make_uint2(0u, 0u);
  if (lane < cnt) wv = bins[(size_t)sb * BCAP + lane];

  int i = 0;
  for (; i + 3 < cnt; i += 4) {   // 4 independent y-loads in flight
    unsigned x0 = (unsigned)__shfl((int)wv.x, i + 0);
    unsigned x1 = (unsigned)__shfl((int)wv.x, i + 1);
    unsigned x2 = (unsigned)__shfl((int)wv.x, i + 2);
    unsigned x3 = (unsigned)__shfl((int)wv.x, i + 3);
    float v0 = __uint_as_float((unsigned)__shfl((int)wv.y, i + 0));
    float v1 = __uint_as_float((unsigned)__shfl((int)wv.y, i + 1));
    float v2 = __uint_as_float((unsigned)__shfl((int)wv.y, i + 2));
    float v3 = __uint_as_float((unsigned)__shfl((int)wv.y, i + 3));
    unsigned u0 = y[(size_t)(x0 & 0xffffu) * 64 + lane];
    unsigned u1 = y[(size_t)(x1 & 0xffffu) * 64 + lane];
    unsigned u2 = y[(size_t)(x2 & 0xffffu) * 64 + lane];
    unsigned u3 = y[(size_t)(x3 & 0xffffu) * 64 + lane];
    int r0 = (int)__builtin_amdgcn_readfirstlane((x0 >> 16) & 3);
    int r1 = (int)__builtin_amdgcn_readfirstlane((x1 >> 16) & 3);
    int r2 = (int)__builtin_amdgcn_readfirstlane((x2 >> 16) & 3);
    int r3 = (int)__builtin_amdgcn_readfirstlane((x3 >> 16) & 3);
    ACC(r0, v0, u0);
    ACC(r1, v1, u1);
    ACC(r2, v2, u2);
    ACC(r3, v3, u3);
  }
  for (; i < cnt; ++i) {          // tail (<=3 singles)
    unsigned x0 = (unsigned)__shfl((int)wv.x, i);
    float v0 = __uint_as_float((unsigned)__shfl((int)wv.y, i));
    unsigned u0 = y[(size_t)(x0 & 0xffffu) * 64 + lane];
    int r0 = (int)__builtin_amdgcn_readfirstlane((x0 >> 16) & 3);
    ACC(r0, v0, u0);
  }

  // overflow entries (expected ~0-10 total): wave 0 scans for this bucket
  if (w == 0) {
    int nof = *ofcnt;
    if (nof > OFCAP) nof = OFCAP;
    for (int k = 0; k < nof; ++k) {
      uint2 o = ofl[k];
      unsigned r = o.x >> 16;
      if ((int)(r >> 2) == bkt) {
        unsigned u = y[(size_t)(o.x & 0xffffu) * 64 + lane];
        float v = __uint_as_float(o.y);
        ACC((int)(r & 3), v, u);
      }
    }
  }
  #undef ACC

  part[w][0][lane] = make_float2(a0L, a0H);
  part[w][1][lane] = make_float2(a1L, a1H);
  part[w][2][lane] = make_float2(a2L, a2H);
  part[w][3][lane] = make_float2(a3L, a3H);
  __syncthreads();

  if (w < 4) {   // wave w reduces row w across the 8 shard partials
    float sL = 0.f, sH = 0.f;
    #pragma unroll
    for (int s = 0; s < 8; ++s) {
      float2 p = part[s][w][lane];
      sL += p.x;
      sH += p.y;
    }
    float2 bv = *(const float2*)&bias[lane * 2];
    float2 o;
    o.x = fmaxf(sL + bv.x, 0.0f);
    o.y = fmaxf(sH + bv.y, 0.0f);
    *(float2*)&out[(size_t)(bkt * 4 + w) * D + lane * 2] = o;
  }
}

extern "C" void kernel_launch(void* const* d_in, const int* in_sizes, int n_in,
                              void* d_out, int out_size, void* d_ws, size_t ws_size,
                              hipStream_t stream) {
  const float* x = (const float*)d_in[0];
  const int* lp_rows = (const int*)d_in[1];
  const int* lp_cols = (const int*)d_in[2];
  const float* lp_vals = (const float*)d_in[3];
  const int* hp_rows = (const int*)d_in[4];
  const int* hp_cols = (const int*)d_in[5];
  const float* hp_vals = (const float*)d_in[6];
  const float* alpha_w = (const float*)d_in[7];
  const float* alpha_b = (const float*)d_in[8];
  const float* W = (const float*)d_in[9];
  const float* bias = (const float*)d_in[10];

  float* out = (float*)d_out;                      // [N, 128]
  float* alpha_out = out + (size_t)N_NODES_C * D;  // [N, 1] output tail

  char* ws = (char*)d_ws;
  unsigned* y = (unsigned*)ws;   ws += (size_t)N_NODES_C * 64 * 4;          // 12.8 MB
  float* alpha_ws = (float*)ws;  ws += 200192;
  int* bcursor = (int*)ws;       ws += (size_t)NSB * 4;                     // 400 KB
  int* ofcnt = (int*)ws;         ws += 256;                                 // adjacent to bcursor
  uint2* ofl = (uint2*)ws;       ws += (size_t)OFCAP * 8;                   // 32 KB
  uint2* bins = (uint2*)ws;
  ws += (size_t)NSB * BCAP * 8;                                            // 25.6 MB

  // Dispatch 1: alpha + cursor/ofcnt zeroing
  alpha_zero_kernel<<<(N_NODES_C + 3) / 4, 256, 0, stream>>>(
      x, alpha_w, alpha_b, alpha_out, alpha_ws, bcursor, N_NODES_C);

  // Dispatch 2: block-specialized gemm || fill (bucketed append)
  gemm_fill_kernel<<<TOTG, 256, 0, stream>>>(
      x, W, y,
      lp_rows, lp_cols, lp_vals, hp_rows, hp_cols, hp_vals,
      alpha_ws, bcursor, bins, ofcnt, ofl, N_NODES_C);

  // Dispatch 3: bucket gather, 8 waves/block (wave = shard), LDS combine
  gather_kernel<<<NBKT, 512, 0, stream>>>(
      bcursor, bins, (const unsigned*)y, bias, ofcnt, ofl, out);
}

// Round 9
// 272.459 us; speedup vs baseline: 1.0637x; 1.0637x over previous
//
#include <hip/hip_runtime.h>

#define N_NODES_C 50000
#define N_EDGES_C 800000
#define N_EDGES2_C (2 * N_EDGES_C)
#define D 128
#define NSHARD 8
#define OFCAP 4096 // overflow list capacity (expected use ~3 edges)

// Bucketed append: BROWS rows per bucket, per-XCD sub-buckets.
#define BROWS 4
#define NBKT (N_NODES_C / BROWS)   // 12500 (exact)
#define NSB (NSHARD * NBKT)        // 100000 sub-buckets
#define BCAP 32                    // entries per sub-bucket (mean 16, +4 sigma)

#define GNODES 64
#define LDP 132                                            // pad: multiple of 4 floats
#define GGRID ((N_NODES_C + GNODES - 1) / GNODES)          // 782 gemm blocks
#define FGRID 2048                                         // fill blocks
#define FEPB ((N_EDGES2_C + FGRID - 1) / FGRID)            // 782 edges/block
#define TOTG (GGRID + FGRID)                               // 2830

static __device__ __forceinline__ unsigned short f2bf(float f) {
  unsigned u = __float_as_uint(f);
  u += 0x7fff + ((u >> 16) & 1);  // round-to-nearest-even
  return (unsigned short)(u >> 16);
}
static __device__ __forceinline__ float bf_lo(unsigned u) {
  return __uint_as_float(u << 16);
}
static __device__ __forceinline__ float bf_hi(unsigned u) {
  return __uint_as_float(u & 0xffff0000u);
}

// Physical XCD id (0..7), wave-uniform; steers L2 locality only.
static __device__ __forceinline__ int xcd_id() {
  int v;
  asm volatile("s_getreg_b32 %0, hwreg(HW_REG_XCC_ID, 0, 4)" : "=s"(v));
  return v & (NSHARD - 1);
}

// ---------------------------------------------------------------------------
// Kernel 1: alpha[i] = sigmoid(dot(x[i], alpha_w) + alpha_b), wave per node,
// PLUS zeroing of bcursor[NSB] and ofcnt (adjacent in ws). (Round-6 verified.)
// ---------------------------------------------------------------------------
__global__ __launch_bounds__(256) void alpha_zero_kernel(
    const float* __restrict__ x,
    const float* __restrict__ aw,
    const float* __restrict__ ab,
    float* __restrict__ alpha_out,
    float* __restrict__ alpha_ws,
    int* __restrict__ bcursor,   // zeroes [0, NSB + 64) ints (incl ofcnt)
    int n) {
  int gtid = blockIdx.x * blockDim.x + threadIdx.x;
  if (gtid < NSB + 64) bcursor[gtid] = 0;

  int wave = gtid >> 6;
  int lane = threadIdx.x & 63;
  if (wave >= n) return;
  const float* xr = x + (size_t)wave * D;
  float s = xr[lane] * aw[lane] + xr[lane + 64] * aw[lane + 64];
  #pragma unroll
  for (int off = 32; off > 0; off >>= 1)
    s += __shfl_down(s, off);
  if (lane == 0) {
    float a = 1.0f / (1.0f + __expf(-(s + ab[0])));
    alpha_out[wave] = a;
    alpha_ws[wave] = a;
  }
}

// ---------------------------------------------------------------------------
// Kernel 2 (FUSED, block-specialized): GGRID gemm blocks + FGRID fill blocks,
// Bresenham-interleaved. (Round-6 verified body, unchanged.)
// ---------------------------------------------------------------------------
__global__ __launch_bounds__(256) void gemm_fill_kernel(
    const float* __restrict__ x,
    const float* __restrict__ W,
    unsigned* __restrict__ y,        // [N][64] packed words
    const int* __restrict__ lp_rows, const int* __restrict__ lp_cols,
    const float* __restrict__ lp_vals,
    const int* __restrict__ hp_rows, const int* __restrict__ hp_cols,
    const float* __restrict__ hp_vals,
    const float* __restrict__ alpha,
    int* __restrict__ bcursor,       // [NSB], zeroed
    uint2* __restrict__ bins,        // [NSB][BCAP]
    int* __restrict__ ofcnt,
    uint2* __restrict__ ofl,
    int n) {
  __shared__ float zs[GNODES][LDP];  // 33.8 KB
  __shared__ float wt[64][LDP];      // 33.8 KB (one j-half of W)

  int t = threadIdx.x;
  int bid = blockIdx.x;
  // Bresenham role split: exactly GGRID gemm blocks spread evenly.
  int g = (bid * GGRID) / TOTG;
  int gn = ((bid + 1) * GGRID) / TOTG;

  if (gn > g) {
    // ---------------- gemm block: nodes [g*64, g*64+64) ----------------
    int node0 = g * GNODES;
    int tn = t & 15;
    int tjg = t >> 4;   // 0..15
    int jb = tjg * 4;   // local j base within this half

    #pragma unroll
    for (int it = 0; it < 8; ++it) {
      int f = t + it * 256;
      int r = f >> 5;
      int c4 = f & 31;
      int node = node0 + r;
      float4 v = make_float4(0.f, 0.f, 0.f, 0.f);
      if (node < n) v = ((const float4*)(x + (size_t)node * D))[c4];
      *(float4*)&zs[r][c4 * 4] = v;
    }

    for (int jh = 0; jh < 2; ++jh) {
      if (jh) __syncthreads();  // half 0's wt readers done before overwrite
      #pragma unroll
      for (int it = 0; it < 8; ++it) {
        int f = t + it * 256;
        int j = f >> 5;
        int k4 = f & 31;
        *(float4*)&wt[j][k4 * 4] =
            ((const float4*)W)[(size_t)(jh * 64 + j) * 32 + k4];
      }
      __syncthreads();

      float acc[4][4] = {};
      #pragma unroll 2
      for (int k = 0; k < D; k += 4) {
        float4 w0 = *(const float4*)&wt[jb + 0][k];
        float4 w1 = *(const float4*)&wt[jb + 1][k];
        float4 w2 = *(const float4*)&wt[jb + 2][k];
        float4 w3 = *(const float4*)&wt[jb + 3][k];
        float4 z0 = *(const float4*)&zs[tn][k];
        float4 z1 = *(const float4*)&zs[tn + 16][k];
        float4 z2 = *(const float4*)&zs[tn + 32][k];
        float4 z3 = *(const float4*)&zs[tn + 48][k];
        acc[0][0] += z0.x*w0.x + z0.y*w0.y + z0.z*w0.z + z0.w*w0.w;
        acc[0][1] += z0.x*w1.x + z0.y*w1.y + z0.z*w1.z + z0.w*w1.w;
        acc[0][2] += z0.x*w2.x + z0.y*w2.y + z0.z*w2.z + z0.w*w2.w;
        acc[0][3] += z0.x*w3.x + z0.y*w3.y + z0.z*w3.z + z0.w*w3.w;
        acc[1][0] += z1.x*w0.x + z1.y*w0.y + z1.z*w0.z + z1.w*w0.w;
        acc[1][1] += z1.x*w1.x + z1.y*w1.y + z1.z*w1.z + z1.w*w1.w;
        acc[1][2] += z1.x*w2.x + z1.y*w2.y + z1.z*w2.z + z1.w*w2.w;
        acc[1][3] += z1.x*w3.x + z1.y*w3.y + z1.z*w3.z + z1.w*w3.w;
        acc[2][0] += z2.x*w0.x + z2.y*w0.y + z2.z*w0.z + z2.w*w0.w;
        acc[2][1] += z2.x*w1.x + z2.y*w1.y + z2.z*w1.z + z2.w*w1.w;
        acc[2][2] += z2.x*w2.x + z2.y*w2.y + z2.z*w2.z + z2.w*w2.w;
        acc[2][3] += z2.x*w3.x + z2.y*w3.y + z2.z*w3.z + z2.w*w3.w;
        acc[3][0] += z3.x*w0.x + z3.y*w0.y + z3.z*w0.z + z3.w*w0.w;
        acc[3][1] += z3.x*w1.x + z3.y*w1.y + z3.z*w1.z + z3.w*w1.w;
        acc[3][2] += z3.x*w2.x + z3.y*w2.y + z3.z*w2.z + z3.w*w2.w;
        acc[3][3] += z3.x*w3.x + z3.y*w3.y + z3.z*w3.z + z3.w*w3.w;
      }

      #pragma unroll
      for (int ii = 0; ii < 4; ++ii) {
        int node = node0 + ii * 16 + tn;
        if (node < n) {
          uint2 o;
          o.x = (unsigned)f2bf(acc[ii][0]) | ((unsigned)f2bf(acc[ii][1]) << 16);
          o.y = (unsigned)f2bf(acc[ii][2]) | ((unsigned)f2bf(acc[ii][3]) << 16);
          *(uint2*)&y[(size_t)node * 64 + jh * 32 + tjg * 2] = o;
        }
      }
    }
  } else {
    // ---------------- fill block: edges [fb*FEPB, fb*FEPB+FEPB) --------
    int fb = bid - g;
    int xcc = xcd_id();
    int e0 = fb * FEPB;
    int e1 = e0 + FEPB;
    if (e1 > N_EDGES2_C) e1 = N_EDGES2_C;
    for (int e = e0 + t; e < e1; e += 256) {
      int r, c;
      float v;
      if (e < N_EDGES_C) {
        r = __builtin_nontemporal_load(lp_rows + e);
        c = __builtin_nontemporal_load(lp_cols + e);
        v = __builtin_nontemporal_load(lp_vals + e) * alpha[r];
      } else {
        int i = e - N_EDGES_C;
        r = __builtin_nontemporal_load(hp_rows + i);
        c = __builtin_nontemporal_load(hp_cols + i);
        v = __builtin_nontemporal_load(hp_vals + i) * (1.0f - alpha[r]);
      }
      int sb = xcc * NBKT + (r >> 2);
      int p = atomicAdd(&bcursor[sb], 1);
      if (p < BCAP) {
        bins[(size_t)sb * BCAP + p] =
            make_uint2(((unsigned)r << 16) | (unsigned)c, __float_as_uint(v));
      } else {
        int q = atomicAdd(ofcnt, 1);
        if (q < OFCAP)
          ofl[q] = make_uint2(((unsigned)r << 16) | (unsigned)c,
                              (unsigned)__float_as_int(v));
      }
    }
  }
}

// ---------------------------------------------------------------------------
// Kernel 3: gather — ONE WAVE PER BUCKET (4 rows), register accumulation in
// NAMED per-row accumulators, NO atomics, NO LDS, NO barriers. Round-6
// structure (best load balance: each wave sums 8 Poisson(16) sub-buckets ->
// +-9% imbalance, vs R8's max-of-8 barrier coupling = +60%).
// CHANGE vs R6 (single variable): inner batch widened 4 -> 8 independent
// y-loads in flight, halving the dependent chain (~32 -> ~16 steps).
// R8 showed short chains help only WITHOUT new sync; this adds depth with
// zero sync cost. All arrays fully unrolled (rule: no runtime indexing).
// ---------------------------------------------------------------------------
__global__ __launch_bounds__(256) void gather_kernel(
    const int* __restrict__ bcursor,     // [NSHARD][NBKT]
    const uint2* __restrict__ bins,      // [NSB][BCAP]
    const unsigned* __restrict__ y,      // [N][64], word q = dims (2q,2q+1)
    const float* __restrict__ bias,
    const int* __restrict__ ofcnt,
    const uint2* __restrict__ ofl,
    float* __restrict__ out) {
  int t = threadIdx.x;
  int w = t >> 6;
  int lane = t & 63;
  int bkt = blockIdx.x * 4 + w;   // 0..12499 (exact: 3125 blocks x 4 waves)

  float a0L = 0.f, a0H = 0.f, a1L = 0.f, a1H = 0.f;
  float a2L = 0.f, a2H = 0.f, a3L = 0.f, a3H = 0.f;

  #define ACC(RR, VV, UU)                                        \
    do {                                                         \
      float uL_ = bf_lo(UU), uH_ = bf_hi(UU);                    \
      switch (RR) {                                              \
        case 0: a0L += (VV) * uL_; a0H += (VV) * uH_; break;     \
        case 1: a1L += (VV) * uL_; a1H += (VV) * uH_; break;     \
        case 2: a2L += (VV) * uL_; a2H += (VV) * uH_; break;     \
        default: a3L += (VV) * uL_; a3H += (VV) * uH_; break;    \
      }                                                          \
    } while (0)

  int cnts[8];
  uint2 wvs[8];
  #pragma unroll
  for (int s = 0; s < 8; ++s) {
    int c = bcursor[s * NBKT + bkt];
    cnts[s] = c > BCAP ? BCAP : c;
  }
  #pragma unroll
  for (int s = 0; s < 8; ++s) {
    wvs[s] = make_uint2(0u, 0u);
    if (lane < cnts[s])
      wvs[s] = bins[(size_t)(s * NBKT + bkt) * BCAP + lane];
  }

  #pragma unroll
  for (int s = 0; s < 8; ++s) {
    int cnt = cnts[s];
    uint2 wv = wvs[s];
    int i = 0;
    for (; i + 7 < cnt; i += 8) {   // 8 independent y-loads in flight
      unsigned xk0 = (unsigned)__shfl((int)wv.x, i + 0);
      unsigned xk1 = (unsigned)__shfl((int)wv.x, i + 1);
      unsigned xk2 = (unsigned)__shfl((int)wv.x, i + 2);
      unsigned xk3 = (unsigned)__shfl((int)wv.x, i + 3);
      unsigned xk4 = (unsigned)__shfl((int)wv.x, i + 4);
      unsigned xk5 = (unsigned)__shfl((int)wv.x, i + 5);
      unsigned xk6 = (unsigned)__shfl((int)wv.x, i + 6);
      unsigned xk7 = (unsigned)__shfl((int)wv.x, i + 7);
      float v0 = __uint_as_float((unsigned)__shfl((int)wv.y, i + 0));
      float v1 = __uint_as_float((unsigned)__shfl((int)wv.y, i + 1));
      float v2 = __uint_as_float((unsigned)__shfl((int)wv.y, i + 2));
      float v3 = __uint_as_float((unsigned)__shfl((int)wv.y, i + 3));
      float v4 = __uint_as_float((unsigned)__shfl((int)wv.y, i + 4));
      float v5 = __uint_as_float((unsigned)__shfl((int)wv.y, i + 5));
      float v6 = __uint_as_float((unsigned)__shfl((int)wv.y, i + 6));
      float v7 = __uint_as_float((unsigned)__shfl((int)wv.y, i + 7));
      unsigned u0 = y[(size_t)(xk0 & 0xffffu) * 64 + lane];
      unsigned u1 = y[(size_t)(xk1 & 0xffffu) * 64 + lane];
      unsigned u2 = y[(size_t)(xk2 & 0xffffu) * 64 + lane];
      unsigned u3 = y[(size_t)(xk3 & 0xffffu) * 64 + lane];
      unsigned u4 = y[(size_t)(xk4 & 0xffffu) * 64 + lane];
      unsigned u5 = y[(size_t)(xk5 & 0xffffu) * 64 + lane];
      unsigned u6 = y[(size_t)(xk6 & 0xffffu) * 64 + lane];
      unsigned u7 = y[(size_t)(xk7 & 0xffffu) * 64 + lane];
      int r0 = (int)__builtin_amdgcn_readfirstlane((xk0 >> 16) & 3);
      int r1 = (int)__builtin_amdgcn_readfirstlane((xk1 >> 16) & 3);
      int r2 = (int)__builtin_amdgcn_readfirstlane((xk2 >> 16) & 3);
      int r3 = (int)__builtin_amdgcn_readfirstlane((xk3 >> 16) & 3);
      int r4 = (int)__builtin_amdgcn_readfirstlane((xk4 >> 16) & 3);
      int r5 = (int)__builtin_amdgcn_readfirstlane((xk5 >> 16) & 3);
      int r6 = (int)__builtin_amdgcn_readfirstlane((xk6 >> 16) & 3);
      int r7 = (int)__builtin_amdgcn_readfirstlane((xk7 >> 16) & 3);
      ACC(r0, v0, u0);
      ACC(r1, v1, u1);
      ACC(r2, v2, u2);
      ACC(r3, v3, u3);
      ACC(r4, v4, u4);
      ACC(r5, v5, u5);
      ACC(r6, v6, u6);
      ACC(r7, v7, u7);
    }
    for (; i + 3 < cnt; i += 4) {   // quad tail
      unsigned xk0 = (unsigned)__shfl((int)wv.x, i + 0);
      unsigned xk1 = (unsigned)__shfl((int)wv.x, i + 1);
      unsigned xk2 = (unsigned)__shfl((int)wv.x, i + 2);
      unsigned xk3 = (unsigned)__shfl((int)wv.x, i + 3);
      float v0 = __uint_as_float((unsigned)__shfl((int)wv.y, i + 0));
      float v1 = __uint_as_float((unsigned)__shfl((int)wv.y, i + 1));
      float v2 = __uint_as_float((unsigned)__shfl((int)wv.y, i + 2));
      float v3 = __uint_as_float((unsigned)__shfl((int)wv.y, i + 3));
      unsigned u0 = y[(size_t)(xk0 & 0xffffu) * 64 + lane];
      unsigned u1 = y[(size_t)(xk1 & 0xffffu) * 64 + lane];
      unsigned u2 = y[(size_t)(xk2 & 0xffffu) * 64 + lane];
      unsigned u3 = y[(size_t)(xk3 & 0xffffu) * 64 + lane];
      int r0 = (int)__builtin_amdgcn_readfirstlane((xk0 >> 16) & 3);
      int r1 = (int)__builtin_amdgcn_readfirstlane((xk1 >> 16) & 3);
      int r2 = (int)__builtin_amdgcn_readfirstlane((xk2 >> 16) & 3);
      int r3 = (int)__builtin_amdgcn_readfirstlane((xk3 >> 16) & 3);
      ACC(r0, v0, u0);
      ACC(r1, v1, u1);
      ACC(r2, v2, u2);
      ACC(r3, v3, u3);
    }
    for (; i < cnt; ++i) {          // singles tail (<=3)
      unsigned xk0 = (unsigned)__shfl((int)wv.x, i);
      float v0 = __uint_as_float((unsigned)__shfl((int)wv.y, i));
      unsigned u0 = y[(size_t)(xk0 & 0xffffu) * 64 + lane];
      int r0 = (int)__builtin_amdgcn_readfirstlane((xk0 >> 16) & 3);
      ACC(r0, v0, u0);
    }
  }

  // overflow entries (expected ~0-10 total): every wave scans, matches own bucket
  int nof = *ofcnt;
  if (nof > OFCAP) nof = OFCAP;
  for (int i = 0; i < nof; ++i) {
    uint2 o = ofl[i];
    unsigned r = o.x >> 16;
    if ((int)(r >> 2) == bkt) {
      unsigned u = y[(size_t)(o.x & 0xffffu) * 64 + lane];
      float v = __uint_as_float(o.y);
      ACC((int)(r & 3), v, u);
    }
  }
  #undef ACC

  float2 bv = *(const float2*)&bias[lane * 2];
  size_t ro = (size_t)bkt * 4 * D + lane * 2;
  float2 o0, o1, o2, o3;
  o0.x = fmaxf(a0L + bv.x, 0.0f); o0.y = fmaxf(a0H + bv.y, 0.0f);
  o1.x = fmaxf(a1L + bv.x, 0.0f); o1.y = fmaxf(a1H + bv.y, 0.0f);
  o2.x = fmaxf(a2L + bv.x, 0.0f); o2.y = fmaxf(a2H + bv.y, 0.0f);
  o3.x = fmaxf(a3L + bv.x, 0.0f); o3.y = fmaxf(a3H + bv.y, 0.0f);
  *(float2*)&out[ro + 0 * D] = o0;
  *(float2*)&out[ro + 1 * D] = o1;
  *(float2*)&out[ro + 2 * D] = o2;
  *(float2*)&out[ro + 3 * D] = o3;
}

extern "C" void kernel_launch(void* const* d_in, const int* in_sizes, int n_in,
                              void* d_out, int out_size, void* d_ws, size_t ws_size,
                              hipStream_t stream) {
  const float* x = (const float*)d_in[0];
  const int* lp_rows = (const int*)d_in[1];
  const int* lp_cols = (const int*)d_in[2];
  const float* lp_vals = (const float*)d_in[3];
  const int* hp_rows = (const int*)d_in[4];
  const int* hp_cols = (const int*)d_in[5];
  const float* hp_vals = (const float*)d_in[6];
  const float* alpha_w = (const float*)d_in[7];
  const float* alpha_b = (const float*)d_in[8];
  const float* W = (const float*)d_in[9];
  const float* bias = (const float*)d_in[10];

  float* out = (float*)d_out;                      // [N, 128]
  float* alpha_out = out + (size_t)N_NODES_C * D;  // [N, 1] output tail

  char* ws = (char*)d_ws;
  unsigned* y = (unsigned*)ws;   ws += (size_t)N_NODES_C * 64 * 4;          // 12.8 MB
  float* alpha_ws = (float*)ws;  ws += 200192;
  int* bcursor = (int*)ws;       ws += (size_t)NSB * 4;                     // 400 KB
  int* ofcnt = (int*)ws;         ws += 256;                                 // adjacent to bcursor
  uint2* ofl = (uint2*)ws;       ws += (size_t)OFCAP * 8;                   // 32 KB
  uint2* bins = (uint2*)ws;
  ws += (size_t)NSB * BCAP * 8;                                            // 25.6 MB

  // Dispatch 1: alpha + cursor/ofcnt zeroing
  alpha_zero_kernel<<<(N_NODES_C + 3) / 4, 256, 0, stream>>>(
      x, alpha_w, alpha_b, alpha_out, alpha_ws, bcursor, N_NODES_C);

  // Dispatch 2: block-specialized gemm || fill (bucketed append)
  gemm_fill_kernel<<<TOTG, 256, 0, stream>>>(
      x, W, y,
      lp_rows, lp_cols, lp_vals, hp_rows, hp_cols, hp_vals,
      alpha_ws, bcursor, bins, ofcnt, ofl, N_NODES_C);

  // Dispatch 3: bucket gather (wave per bucket, 8-deep MLP)
  gather_kernel<<<NBKT / 4, 256, 0, stream>>>(
      bcursor, bins, (const unsigned*)y, bias, ofcnt, ofl, out);
}